// Round 1
// baseline (526.926 us; speedup 1.0000x reference)
//
#include <hip/hip_runtime.h>
#include <stdint.h>

#define LRELU(x) ((x) > 0.0f ? (x) : 0.01f * (x))

// ---------------- CSR build ----------------

__global__ void count_kernel(const int* __restrict__ dst, int* __restrict__ cnt, int E) {
    int e = blockIdx.x * blockDim.x + threadIdx.x;
    if (e < E) atomicAdd(&cnt[dst[e]], 1);
}

__global__ void dinv_kernel(const int* __restrict__ cnt, float* __restrict__ dinv, int N) {
    int i = blockIdx.x * blockDim.x + threadIdx.x;
    if (i < N) dinv[i] = rsqrtf((float)cnt[i] + 1.0f);  // +1 self loop
}

// per-block exclusive scan of cnt into row_ptr (local), block sums into part[]
__global__ void scan1_kernel(const int* __restrict__ cnt, int* __restrict__ row_ptr,
                             int* __restrict__ part, int N) {
    __shared__ int s[256];
    int t = threadIdx.x;
    int i = blockIdx.x * 256 + t;
    int v = (i < N) ? cnt[i] : 0;
    s[t] = v;
    __syncthreads();
    for (int off = 1; off < 256; off <<= 1) {
        int a = (t >= off) ? s[t - off] : 0;
        __syncthreads();
        s[t] += a;
        __syncthreads();
    }
    if (i < N) row_ptr[i] = s[t] - v;          // local exclusive
    if (t == 255) part[blockIdx.x] = s[255];   // block total
}

// single-block exclusive scan of block sums (nb <= 1024)
__global__ void scan2_kernel(int* __restrict__ part, int nb) {
    __shared__ int s[1024];
    int t = threadIdx.x;
    int v = (t < nb) ? part[t] : 0;
    s[t] = v;
    __syncthreads();
    for (int off = 1; off < 1024; off <<= 1) {
        int a = (t >= off) ? s[t - off] : 0;
        __syncthreads();
        s[t] += a;
        __syncthreads();
    }
    if (t < nb) part[t] = s[t] - v;            // exclusive
}

__global__ void scan3_kernel(int* __restrict__ row_ptr, const int* __restrict__ part,
                             int* __restrict__ cursor, int N, int E) {
    int i = blockIdx.x * blockDim.x + threadIdx.x;
    if (i < N) {
        int rp = row_ptr[i] + part[i >> 8];
        row_ptr[i] = rp;
        cursor[i] = rp;
        if (i == 0) row_ptr[N] = E;
    }
}

__global__ void scatter_kernel(const int* __restrict__ src, const int* __restrict__ dst,
                               const float* __restrict__ dinv, int* __restrict__ cursor,
                               int* __restrict__ csr_src, float* __restrict__ csr_w, int E) {
    int e = blockIdx.x * blockDim.x + threadIdx.x;
    if (e < E) {
        int s = src[e], d = dst[e];
        int pos = atomicAdd(&cursor[d], 1);
        csr_src[pos] = s;
        csr_w[pos] = dinv[s] * dinv[d];
    }
}

// ---------------- GCN layer ----------------

// H = X @ W   (X: [N,64], W: [64,64] row-major)
__global__ __launch_bounds__(256) void gemm_kernel(const float* __restrict__ X,
                                                   const float* __restrict__ W,
                                                   float* __restrict__ H, int N) {
    __shared__ float xl[64 * 66];   // padded: bank-conflict-free node-indexed reads
    __shared__ float wl[64 * 64];
    int tid = threadIdx.x;
    int base = blockIdx.x * 64;
    #pragma unroll
    for (int i = 0; i < 16; ++i) wl[i * 256 + tid] = W[i * 256 + tid];
    #pragma unroll
    for (int i = 0; i < 16; ++i) {
        int idx = i * 256 + tid;
        int r = idx >> 6, c = idx & 63;
        int gr = base + r;
        xl[r * 66 + c] = (gr < N) ? X[gr * 64 + c] : 0.0f;
    }
    __syncthreads();
    int grp = tid >> 4;            // 0..15 -> 4 nodes each
    int f0 = (tid & 15) * 4;       // 4 features each
    int n0 = grp * 4;
    float acc[4][4] = {};
    #pragma unroll 4
    for (int k = 0; k < 64; ++k) {
        float4 wv = *(const float4*)&wl[k * 64 + f0];
        #pragma unroll
        for (int j = 0; j < 4; ++j) {
            float xv = xl[(n0 + j) * 66 + k];
            acc[j][0] += xv * wv.x;
            acc[j][1] += xv * wv.y;
            acc[j][2] += xv * wv.z;
            acc[j][3] += xv * wv.w;
        }
    }
    #pragma unroll
    for (int j = 0; j < 4; ++j) {
        int gr = base + n0 + j;
        if (gr < N)
            *(float4*)&H[gr * 64 + f0] =
                make_float4(acc[j][0], acc[j][1], acc[j][2], acc[j][3]);
    }
}

// Y[v] = leaky( sum_in-edges w*H[src] + dinv[v]^2 * H[v] + bias )
__global__ __launch_bounds__(256) void agg_kernel(const float* __restrict__ H,
                                                  const int* __restrict__ rp,
                                                  const int* __restrict__ csrc,
                                                  const float* __restrict__ cw,
                                                  const float* __restrict__ dinv,
                                                  const float* __restrict__ bias,
                                                  float* __restrict__ Y, int N) {
    int wid = (blockIdx.x * blockDim.x + threadIdx.x) >> 6;  // wave = node
    int f = threadIdx.x & 63;                                // lane = feature
    if (wid >= N) return;
    float dv = dinv[wid];
    float acc = H[wid * 64 + f] * dv * dv;
    int e = rp[wid], end = rp[wid + 1];
    for (; e + 4 <= end; e += 4) {
        int s0 = csrc[e], s1 = csrc[e + 1], s2 = csrc[e + 2], s3 = csrc[e + 3];
        float w0 = cw[e], w1 = cw[e + 1], w2 = cw[e + 2], w3 = cw[e + 3];
        acc += w0 * H[s0 * 64 + f] + w1 * H[s1 * 64 + f] +
               w2 * H[s2 * 64 + f] + w3 * H[s3 * 64 + f];
    }
    for (; e < end; ++e) acc += cw[e] * H[csrc[e] * 64 + f];
    Y[wid * 64 + f] = LRELU(acc + bias[f]);
}

// ---------------- pooling + MLP ----------------

__global__ void bounds_kernel(const int* __restrict__ batch, int* __restrict__ gstart,
                              int N, int NG) {
    int i = blockIdx.x * blockDim.x + threadIdx.x;
    if (i >= N) return;
    int b = batch[i];
    if (i == 0) {
        gstart[b] = 0;
        gstart[NG] = N;
    } else if (batch[i - 1] != b) {
        gstart[b] = i;
    }
}

__global__ __launch_bounds__(256) void pool_kernel(const float* __restrict__ Y,
                                                   const int* __restrict__ gstart,
                                                   const float* __restrict__ gfeat,
                                                   float* __restrict__ hcat, int NG) {
    __shared__ float ssum[4][64];
    __shared__ float smax[4][64];
    int g = blockIdx.x;
    int f = threadIdx.x & 63;
    int rg = threadIdx.x >> 6;
    int s = gstart[g], epos = gstart[g + 1];
    float sum = 0.f, mx = -3.0e38f;
    for (int r = s + rg; r < epos; r += 4) {
        float v = Y[r * 64 + f];
        sum += v;
        mx = fmaxf(mx, v);
    }
    ssum[rg][f] = sum;
    smax[rg][f] = mx;
    __syncthreads();
    if (rg == 0) {
        float ts = ssum[0][f] + ssum[1][f] + ssum[2][f] + ssum[3][f];
        float tm = fmaxf(fmaxf(smax[0][f], smax[1][f]), fmaxf(smax[2][f], smax[3][f]));
        float cnt = (float)(epos - s);
        hcat[g * 160 + f] = ts / cnt;
        hcat[g * 160 + 64 + f] = tm;
    }
    if (threadIdx.x < 32) hcat[g * 160 + 128 + threadIdx.x] = gfeat[g * 32 + threadIdx.x];
}

__global__ __launch_bounds__(256) void mlp_kernel(const float* __restrict__ hcat,
                                                  const float* __restrict__ w1,
                                                  const float* __restrict__ b1,
                                                  const float* __restrict__ w2,
                                                  const float* __restrict__ b2,
                                                  const float* __restrict__ w3,
                                                  const float* __restrict__ b3,
                                                  float* __restrict__ out, int NG) {
    __shared__ float hl[160];
    __shared__ float h1[256];
    __shared__ float red[128];
    int g = blockIdx.x, t = threadIdx.x;
    if (t < 160) hl[t] = hcat[g * 160 + t];
    __syncthreads();
    float a1 = b1[t];
    for (int k = 0; k < 160; ++k) a1 += hl[k] * w1[k * 256 + t];
    h1[t] = LRELU(a1);
    __syncthreads();
    if (t < 128) {
        float a2 = b2[t];
        for (int k = 0; k < 256; ++k) a2 += h1[k] * w2[k * 128 + t];
        red[t] = LRELU(a2) * w3[t];
    }
    __syncthreads();
    if (t == 0) {
        float a3 = b3[0];
        for (int k = 0; k < 128; ++k) a3 += red[k];
        out[g] = a3;
    }
}

// ---------------- launch ----------------

extern "C" void kernel_launch(void* const* d_in, const int* in_sizes, int n_in,
                              void* d_out, int out_size, void* d_ws, size_t ws_size,
                              hipStream_t stream) {
    const float* x      = (const float*)d_in[0];
    const float* gfeat  = (const float*)d_in[1];
    const float* cw1    = (const float*)d_in[2];
    const float* cb1    = (const float*)d_in[3];
    const float* cw2    = (const float*)d_in[4];
    const float* cb2    = (const float*)d_in[5];
    const float* cw3    = (const float*)d_in[6];
    const float* cb3    = (const float*)d_in[7];
    const float* fw1    = (const float*)d_in[8];
    const float* fb1    = (const float*)d_in[9];
    const float* fw2    = (const float*)d_in[10];
    const float* fb2    = (const float*)d_in[11];
    const float* ow     = (const float*)d_in[12];
    const float* ob     = (const float*)d_in[13];
    const int*   eidx   = (const int*)d_in[14];
    const int*   batch  = (const int*)d_in[15];

    const int N  = in_sizes[0] / 64;
    const int E  = in_sizes[14] / 2;
    const int NG = in_sizes[1] / 32;
    const int* src = eidx;
    const int* dst = eidx + E;

    // workspace carve-out (256B aligned)
    char* wp = (char*)d_ws;
    auto carve = [&](size_t bytes) {
        void* p = (void*)wp;
        wp += (bytes + 255) & ~(size_t)255;
        return p;
    };
    float* dinv    = (float*)carve((size_t)N * 4);
    int*   degcnt  = (int*)  carve((size_t)N * 4);
    int*   row_ptr = (int*)  carve((size_t)(N + 1) * 4);
    int*   cursor  = (int*)  carve((size_t)N * 4);
    int*   part    = (int*)  carve(1024 * 4);
    int*   csr_src = (int*)  carve((size_t)E * 4);
    float* csr_w   = (float*)carve((size_t)E * 4);
    float* hbuf    = (float*)carve((size_t)N * 64 * 4);
    float* ybuf    = (float*)carve((size_t)N * 64 * 4);
    int*   gstart  = (int*)  carve((size_t)(NG + 1) * 4);
    float* hcat    = (float*)carve((size_t)NG * 160 * 4);
    float* outf    = (float*)d_out;

    const int nbN = (N + 255) / 256;
    const int nbE = (E + 255) / 256;

    hipMemsetAsync(degcnt, 0, (size_t)N * 4, stream);
    count_kernel<<<nbE, 256, 0, stream>>>(dst, degcnt, E);
    dinv_kernel<<<nbN, 256, 0, stream>>>(degcnt, dinv, N);
    scan1_kernel<<<nbN, 256, 0, stream>>>(degcnt, row_ptr, part, N);
    scan2_kernel<<<1, 1024, 0, stream>>>(part, nbN);
    scan3_kernel<<<nbN, 256, 0, stream>>>(row_ptr, part, cursor, N, E);
    scatter_kernel<<<nbE, 256, 0, stream>>>(src, dst, dinv, cursor, csr_src, csr_w, E);
    bounds_kernel<<<nbN, 256, 0, stream>>>(batch, gstart, N, NG);

    const int gemmB = (N + 63) / 64;
    const int aggB  = (N + 3) / 4;

    gemm_kernel<<<gemmB, 256, 0, stream>>>(x, cw1, hbuf, N);
    agg_kernel<<<aggB, 256, 0, stream>>>(hbuf, row_ptr, csr_src, csr_w, dinv, cb1, ybuf, N);
    gemm_kernel<<<gemmB, 256, 0, stream>>>(ybuf, cw2, hbuf, N);
    agg_kernel<<<aggB, 256, 0, stream>>>(hbuf, row_ptr, csr_src, csr_w, dinv, cb2, ybuf, N);
    gemm_kernel<<<gemmB, 256, 0, stream>>>(ybuf, cw3, hbuf, N);
    agg_kernel<<<aggB, 256, 0, stream>>>(hbuf, row_ptr, csr_src, csr_w, dinv, cb3, ybuf, N);

    pool_kernel<<<NG, 256, 0, stream>>>(ybuf, gstart, gfeat, hcat, NG);
    mlp_kernel<<<NG, 256, 0, stream>>>(hcat, fw1, fb1, fw2, fb2, ow, ob, outf, NG);
}